// Round 4
// baseline (590.666 us; speedup 1.0000x reference)
//
#include <hip/hip_runtime.h>
#include <hip/hip_bf16.h>

typedef __attribute__((ext_vector_type(8))) short bf16x8;
typedef __attribute__((ext_vector_type(4))) float f32x4;

#define D_MODEL 512
#define NHEAD 8
#define HDIM 64
#define SEQ 4096
#define BATCH 2
#define MTOT (BATCH*SEQ)   // 8192

__device__ __forceinline__ unsigned short f2bf(float f) {
  unsigned int u = __builtin_bit_cast(unsigned int, f);
  u += 0x7FFFu + ((u >> 16) & 1u);   // RNE
  return (unsigned short)(u >> 16);
}

// ---------------------------------------------------------------------------
// fp32 -> bf16 bulk convert (vectorized float4 -> ushort4)
// ---------------------------------------------------------------------------
__global__ __launch_bounds__(256)
void cvt_k(const float* __restrict__ src, unsigned short* __restrict__ dst, int n4) {
  int i = blockIdx.x * blockDim.x + threadIdx.x;
  int stride = gridDim.x * blockDim.x;
  for (; i < n4; i += stride) {
    float4 v = ((const float4*)src)[i];
    ushort4 u = { f2bf(v.x), f2bf(v.y), f2bf(v.z), f2bf(v.w) };
    ((ushort4*)dst)[i] = u;
  }
}

// 4 weight matrices in one launch: blockIdx.y picks the tensor.
__global__ __launch_bounds__(256)
void cvt_w4(const float* __restrict__ w0, const float* __restrict__ w1,
            const float* __restrict__ w2, const float* __restrict__ w3,
            unsigned short* __restrict__ dst, int n4each) {
  const float* srcs[4] = { w0, w1, w2, w3 };
  const float* src = srcs[blockIdx.y];
  unsigned short* d = dst + (size_t)blockIdx.y * n4each * 4;
  int i = blockIdx.x * blockDim.x + threadIdx.x;
  int stride = gridDim.x * blockDim.x;
  for (; i < n4each; i += stride) {
    float4 v = ((const float4*)src)[i];
    ushort4 u = { f2bf(v.x), f2bf(v.y), f2bf(v.z), f2bf(v.w) };
    ((ushort4*)(d))[i] = u;
  }
}

// ---------------------------------------------------------------------------
// GEMM: C[M=8192, N=512] = A[M,K=512] @ W[N,K]^T + bias. A, W already bf16.
// m97 structure: 128x128 tile, BK=64, 4 waves (2x2, 64x64 each), linear LDS,
// global_load_lds width=16 staging, 2-barrier K-loop. (T2 swizzle omitted:
// null on 128^2 + 2-phase per regime gate; stall is the barrier drain.)
// OMODE 0: write bf16 [B,H,S,Dh]   (Q, K)
// OMODE 1: write bf16 [B,H,Dh,S]   (V transposed for PV fragment loads)
// OMODE 2: write fp32 [M,N] row-major (final output)
// ---------------------------------------------------------------------------
template<int OMODE>
__global__ __launch_bounds__(256)
void gemm_bf(const unsigned short* __restrict__ A,
             const unsigned short* __restrict__ Bw,
             const float* __restrict__ bias, void* __restrict__ outv, float scale) {
  __shared__ unsigned short Als[128*64];
  __shared__ unsigned short Bls[128*64];
  const int tid = threadIdx.x;
  const int lane = tid & 63, wid = tid >> 6;
  const int wr = wid >> 1, wc = wid & 1;
  const int l15 = lane & 15, l4 = lane >> 4;
  const int m0 = blockIdx.x * 128;
  const int n0 = blockIdx.y * 128;
  // staging coords: wave `wid` issue j covers LDS rows [wid*32 + j*8, +8);
  // per-lane LDS byte addr == wave base + lane*16 (global_load_lds requirement)
  const int srow = lane >> 3;          // row within the 8-row chunk
  const int scol = (lane & 7) * 8;     // elem col (8 bf16 = 16 B per lane)
  f32x4 acc[4][4] = {};

  for (int kt = 0; kt < D_MODEL; kt += 64) {
    #pragma unroll
    for (int j = 0; j < 4; ++j) {
      int r = wid*32 + j*8 + srow;
      __builtin_amdgcn_global_load_lds(
        (const __attribute__((address_space(1))) unsigned int*)(A + (size_t)(m0 + r)*D_MODEL + kt + scol),
        (__attribute__((address_space(3))) unsigned int*)(&Als[r*64 + scol]), 16, 0, 0);
      __builtin_amdgcn_global_load_lds(
        (const __attribute__((address_space(1))) unsigned int*)(Bw + (size_t)(n0 + r)*D_MODEL + kt + scol),
        (__attribute__((address_space(3))) unsigned int*)(&Bls[r*64 + scol]), 16, 0, 0);
    }
    __syncthreads();
    #pragma unroll
    for (int ks = 0; ks < 2; ++ks) {
      bf16x8 a[4], b[4];
      #pragma unroll
      for (int m = 0; m < 4; ++m)
        a[m] = *(const bf16x8*)&Als[(wr*64 + m*16 + l15)*64 + ks*32 + l4*8];
      #pragma unroll
      for (int n = 0; n < 4; ++n)
        b[n] = *(const bf16x8*)&Bls[(wc*64 + n*16 + l15)*64 + ks*32 + l4*8];
      #pragma unroll
      for (int m = 0; m < 4; ++m)
        #pragma unroll
        for (int n = 0; n < 4; ++n)
          acc[m][n] = __builtin_amdgcn_mfma_f32_16x16x32_bf16(a[m], b[n], acc[m][n], 0, 0, 0);
    }
    __syncthreads();
  }

  #pragma unroll
  for (int n = 0; n < 4; ++n) {
    int gn = n0 + wc*64 + n*16 + l15;
    float bv = bias[gn];
    #pragma unroll
    for (int m = 0; m < 4; ++m) {
      int gmb = m0 + wr*64 + m*16 + l4*4;
      #pragma unroll
      for (int r = 0; r < 4; ++r) {
        int gm = gmb + r;
        float val = (acc[m][n][r] + bv) * scale;
        if (OMODE == 2) {
          ((float*)outv)[(size_t)gm*D_MODEL + gn] = val;
        } else {
          int b = gm >> 12, s = gm & 4095;
          int h = gn >> 6, d = gn & 63;
          if (OMODE == 0)
            ((unsigned short*)outv)[((size_t)((b*NHEAD + h)*SEQ + s))*HDIM + d] = f2bf(val);
          else
            ((unsigned short*)outv)[((size_t)((b*NHEAD + h)*HDIM + d))*SEQ + s] = f2bf(val);
        }
      }
    }
  }
}

// ---------------------------------------------------------------------------
// Flash attention. Grid: (SEQ/64, B*H). Block: 256 threads = 4 waves.
// Each wave owns 16 Q rows; iterates over 64-key tiles.
// Q pre-scaled by 1/8 at projection. K read [B,H,S,Dh]; V read [B,H,Dh,S]
// (both L2-resident per head: 512 KB each — no LDS staging, common-mistake #7).
// S-tile D-layout: row=(lane>>4)*4+r (q), col=lane&15 (key). Row reductions
// via shfl_xor masks 1,2,4,8 (stay within 16-lane group).
// P converted to A-fragment layout via wave-private LDS (no block barriers).
// T5: setprio(1) around pure-MFMA clusters.
// T13: defer-max (RESCALE_THRESHOLD=8) skips the O/l rescale on no-growth tiles.
// T14-style: V loads + next-tile K prefetch issued right after QK^T so their
// L2 latency hides under the softmax VALU phase; K ping-pong (kfA/kfB) is
// compile-time-named (rule #20: no runtime-indexed ext_vector arrays).
// ---------------------------------------------------------------------------
__global__ __launch_bounds__(256)
void attn_k(const unsigned short* __restrict__ qw,
            const unsigned short* __restrict__ kw,
            const unsigned short* __restrict__ vtw,
            unsigned short* __restrict__ ctx) {
  __shared__ unsigned short Pls[4][16*72];
  const int tid = threadIdx.x;
  const int lane = tid & 63, wid = tid >> 6;
  const int l15 = lane & 15, l4 = lane >> 4;
  const int bh = blockIdx.y;                    // b*8 + h
  const int q0 = blockIdx.x * 64 + wid * 16;    // this wave's first q row
  const unsigned short* qb = qw + (size_t)bh * SEQ * HDIM;
  const unsigned short* kb = kw + (size_t)bh * SEQ * HDIM;
  const unsigned short* vb = vtw + (size_t)bh * HDIM * SEQ;
  unsigned short* Pw = &Pls[wid][0];

  // Q fragments (A-operand): row=l15, k=l4*8+j (+32 for ks=1). Resident all kernel.
  bf16x8 qf[2];
  qf[0] = *(const bf16x8*)&qb[(size_t)(q0 + l15)*HDIM + l4*8];
  qf[1] = *(const bf16x8*)&qb[(size_t)(q0 + l15)*HDIM + 32 + l4*8];

  f32x4 o[4] = {};
  float mrow[4] = {-1e30f, -1e30f, -1e30f, -1e30f};
  float lrow[4] = {0.f, 0.f, 0.f, 0.f};

  // K ping-pong buffers; preload tile 0 into kfA.
  bf16x8 kfA[4][2], kfB[4][2];
  #pragma unroll
  for (int n = 0; n < 4; ++n) {
    kfA[n][0] = *(const bf16x8*)&kb[(size_t)(n*16 + l15)*HDIM + l4*8];
    kfA[n][1] = *(const bf16x8*)&kb[(size_t)(n*16 + l15)*HDIM + 32 + l4*8];
  }

  auto body = [&](int kt, bf16x8 (&kfU)[4][2], bf16x8 (&kfP)[4][2], int ktp) {
    // ---- S = Q K^T (pure MFMA, prio 1) ----
    f32x4 s[4] = {};
    __builtin_amdgcn_s_setprio(1);
    #pragma unroll
    for (int n = 0; n < 4; ++n) {
      s[n] = __builtin_amdgcn_mfma_f32_16x16x32_bf16(qf[0], kfU[n][0], s[n], 0, 0, 0);
      s[n] = __builtin_amdgcn_mfma_f32_16x16x32_bf16(qf[1], kfU[n][1], s[n], 0, 0, 0);
    }
    __builtin_amdgcn_s_setprio(0);
    // ---- issue V (current tile) + K (tile ktp) loads; latency hides under softmax ----
    bf16x8 vf[4][2];
    #pragma unroll
    for (int n = 0; n < 4; ++n) {
      vf[n][0] = *(const bf16x8*)&vb[(size_t)(n*16 + l15)*SEQ + kt + l4*8];
      vf[n][1] = *(const bf16x8*)&vb[(size_t)(n*16 + l15)*SEQ + kt + 32 + l4*8];
    }
    #pragma unroll
    for (int n = 0; n < 4; ++n) {
      kfP[n][0] = *(const bf16x8*)&kb[(size_t)(ktp + n*16 + l15)*HDIM + l4*8];
      kfP[n][1] = *(const bf16x8*)&kb[(size_t)(ktp + n*16 + l15)*HDIM + 32 + l4*8];
    }
    // ---- online softmax with defer-max (T13, THR=8) ----
    float rmax[4], rsum[4];
    #pragma unroll
    for (int r = 0; r < 4; ++r)
      rmax[r] = fmaxf(fmaxf(s[0][r], s[1][r]), fmaxf(s[2][r], s[3][r]));
    #pragma unroll
    for (int r = 0; r < 4; ++r) {
      rmax[r] = fmaxf(rmax[r], __shfl_xor(rmax[r], 1));
      rmax[r] = fmaxf(rmax[r], __shfl_xor(rmax[r], 2));
      rmax[r] = fmaxf(rmax[r], __shfl_xor(rmax[r], 4));
      rmax[r] = fmaxf(rmax[r], __shfl_xor(rmax[r], 8));
    }
    bool grow = (rmax[0] > mrow[0] + 8.f) || (rmax[1] > mrow[1] + 8.f) ||
                (rmax[2] > mrow[2] + 8.f) || (rmax[3] > mrow[3] + 8.f);
    if (__any(grow)) {
      float alpha[4];
      #pragma unroll
      for (int r = 0; r < 4; ++r) {
        float mn = fmaxf(mrow[r], rmax[r]);
        alpha[r] = __expf(mrow[r] - mn);
        mrow[r] = mn;
        lrow[r] *= alpha[r];
      }
      #pragma unroll
      for (int n = 0; n < 4; ++n)
        #pragma unroll
        for (int r = 0; r < 4; ++r)
          o[n][r] *= alpha[r];
    }
    #pragma unroll
    for (int n = 0; n < 4; ++n)
      #pragma unroll
      for (int r = 0; r < 4; ++r)
        s[n][r] = __expf(s[n][r] - mrow[r]);
    #pragma unroll
    for (int r = 0; r < 4; ++r)
      rsum[r] = (s[0][r] + s[1][r]) + (s[2][r] + s[3][r]);
    #pragma unroll
    for (int r = 0; r < 4; ++r) {
      rsum[r] += __shfl_xor(rsum[r], 1);
      rsum[r] += __shfl_xor(rsum[r], 2);
      rsum[r] += __shfl_xor(rsum[r], 4);
      rsum[r] += __shfl_xor(rsum[r], 8);
      lrow[r] += rsum[r];
    }
    // ---- P: D-layout -> LDS -> A-fragment layout (wave-private, no barrier) ----
    #pragma unroll
    for (int n = 0; n < 4; ++n)
      #pragma unroll
      for (int r = 0; r < 4; ++r)
        Pw[(l4*4 + r)*72 + n*16 + l15] = f2bf(s[n][r]);
    bf16x8 pa0 = *(const bf16x8*)&Pw[l15*72 + l4*8];
    bf16x8 pa1 = *(const bf16x8*)&Pw[l15*72 + 32 + l4*8];
    // ---- O += P V (pure MFMA, prio 1) ----
    __builtin_amdgcn_s_setprio(1);
    #pragma unroll
    for (int n = 0; n < 4; ++n) {
      o[n] = __builtin_amdgcn_mfma_f32_16x16x32_bf16(pa0, vf[n][0], o[n], 0, 0, 0);
      o[n] = __builtin_amdgcn_mfma_f32_16x16x32_bf16(pa1, vf[n][1], o[n], 0, 0, 0);
    }
    __builtin_amdgcn_s_setprio(0);
  };

  for (int kt = 0; kt < SEQ; kt += 128) {
    body(kt,      kfA, kfB, kt + 64);
    body(kt + 64, kfB, kfA, (kt + 128) & (SEQ - 1));  // last prefetch wraps (valid mem, unused)
  }

  // ---- epilogue: O / l -> ctx [B,S,D_MODEL] bf16 ----
  const int b = bh >> 3, h = bh & 7;
  float inv[4];
  #pragma unroll
  for (int r = 0; r < 4; ++r) inv[r] = 1.0f / lrow[r];
  #pragma unroll
  for (int n = 0; n < 4; ++n)
    #pragma unroll
    for (int r = 0; r < 4; ++r) {
      int srow = q0 + l4*4 + r;
      ctx[((size_t)(b*SEQ + srow))*D_MODEL + h*HDIM + n*16 + l15] = f2bf(o[n][r]*inv[r]);
    }
}

extern "C" void kernel_launch(void* const* d_in, const int* in_sizes, int n_in,
                              void* d_out, int out_size, void* d_ws, size_t ws_size,
                              hipStream_t stream) {
  const float* x  = (const float*)d_in[0];
  const float* Wq = (const float*)d_in[1];
  const float* bq = (const float*)d_in[2];
  const float* Wk = (const float*)d_in[3];
  const float* bk = (const float*)d_in[4];
  const float* Wv = (const float*)d_in[5];
  const float* bv = (const float*)d_in[6];
  const float* Wo = (const float*)d_in[7];
  const float* bo = (const float*)d_in[8];

  unsigned short* qw  = (unsigned short*)d_ws;                 // [B,H,S,Dh] bf16, 8 MB
  unsigned short* kw  = qw  + (size_t)MTOT*D_MODEL;            // [B,H,S,Dh] bf16, 8 MB
  unsigned short* vtw = kw  + (size_t)MTOT*D_MODEL;            // [B,H,Dh,S] bf16, 8 MB
  unsigned short* ctx = vtw + (size_t)MTOT*D_MODEL;            // [B,S,D]    bf16, 8 MB
  unsigned short* xb  = ctx + (size_t)MTOT*D_MODEL;            // [M,512]    bf16, 8 MB
  unsigned short* wqb = xb  + (size_t)MTOT*D_MODEL;            // 4x [512,512] bf16 contiguous
  unsigned short* wkb = wqb + (size_t)D_MODEL*D_MODEL;
  unsigned short* wvb = wkb + (size_t)D_MODEL*D_MODEL;
  unsigned short* wob = wvb + (size_t)D_MODEL*D_MODEL;

  dim3 bb(256);
  cvt_k<<<2048, bb, 0, stream>>>(x, xb, MTOT*D_MODEL/4);
  cvt_w4<<<dim3(128, 4), bb, 0, stream>>>(Wq, Wk, Wv, Wo, wqb, D_MODEL*D_MODEL/4);

  dim3 gg(MTOT/128, D_MODEL/128);
  gemm_bf<0><<<gg, bb, 0, stream>>>(xb, wqb, bq, qw, 0.125f);  // Q, pre-scaled 1/sqrt(64)
  gemm_bf<0><<<gg, bb, 0, stream>>>(xb, wkb, bk, kw, 1.0f);    // K
  gemm_bf<1><<<gg, bb, 0, stream>>>(xb, wvb, bv, vtw, 1.0f);   // V transposed
  attn_k<<<dim3(SEQ/64, BATCH*NHEAD), bb, 0, stream>>>(qw, kw, vtw, ctx);
  gemm_bf<2><<<gg, bb, 0, stream>>>(ctx, wob, bo, d_out, 1.0f);
}